// Round 1
// baseline (116.377 us; speedup 1.0000x reference)
//
#include <hip/hip_runtime.h>
#include <hip/hip_bf16.h>

#define N_ROWS 8192   // inputs rows (n)
#define K_CENT 1024   // centers rows (m)
#define DIM    1024   // d

typedef __attribute__((ext_vector_type(8))) __bf16 bf16x8;
typedef __attribute__((ext_vector_type(4))) float  f32x4;

__device__ __forceinline__ unsigned short f2b(float f) {
    union { float f; unsigned u; } x; x.f = f;
    unsigned r = x.u + 0x7FFFu + ((x.u >> 16) & 1u);   // RNE to bf16
    return (unsigned short)(r >> 16);
}

// ---------------- kernel 1: row norms (fp32 exact) ----------------
__global__ __launch_bounds__(256) void norms_kernel(
        const float* __restrict__ inputs, const float* __restrict__ centers,
        float* __restrict__ x_sq, float* __restrict__ c_sq) {
    int row = blockIdx.x;
    const float* src = (row < N_ROWS) ? (inputs + (size_t)row * DIM)
                                      : (centers + (size_t)(row - N_ROWS) * DIM);
    int t = threadIdx.x;
    float4 v = ((const float4*)src)[t];       // 256 thr * 4 = 1024 elems
    float s = v.x*v.x + v.y*v.y + v.z*v.z + v.w*v.w;
    #pragma unroll
    for (int off = 32; off > 0; off >>= 1) s += __shfl_down(s, off, 64);
    __shared__ float wsum[4];
    if ((t & 63) == 0) wsum[t >> 6] = s;
    __syncthreads();
    if (t == 0) {
        float tot = wsum[0] + wsum[1] + wsum[2] + wsum[3];
        if (row < N_ROWS) x_sq[row] = tot;
        else              c_sq[row - N_ROWS] = tot;
    }
}

// ---------------- kernel 2: bf16 MFMA GEMM + epilogue ----------------
// C[m][n] = 2 * sum_d centers[m][d]*inputs[n][d] - c_sq[m] - x_sq[n]
// 128x128 tile per block (256 thr = 4 waves, each wave 64x64), BK=64.
#define BM 128
#define BN 128
#define BK 64
#define LDS_STRIDE 72   // bf16 elems; 144 B row stride -> 2-way (free) bank aliasing

__global__ __launch_bounds__(256) void gemm_kernel(
        const float* __restrict__ inputs,   // N_ROWS x DIM
        const float* __restrict__ centers,  // K_CENT x DIM
        const float* __restrict__ x_sq, const float* __restrict__ c_sq,
        float* __restrict__ out) {          // K_CENT x N_ROWS
    __shared__ unsigned short sA[BM * LDS_STRIDE];
    __shared__ unsigned short sB[BN * LDS_STRIDE];

    const int t    = threadIdx.x;
    const int lane = t & 63;
    const int wave = t >> 6;
    const int wm = (wave >> 1) * 64;        // wave's m offset in tile
    const int wn = (wave & 1) * 64;        // wave's n offset in tile
    const int m0 = blockIdx.y * BM;
    const int n0 = blockIdx.x * BN;

    f32x4 acc[4][4] = {};                   // [mi][ni]

    for (int k0 = 0; k0 < DIM; k0 += BK) {
        // stage A (centers) and B (inputs): 128x64 fp32 -> bf16 each.
        // chunk = 4 elems; 2048 chunks per tile; 8 iters x 256 thr.
        #pragma unroll
        for (int i = 0; i < 8; ++i) {
            int chunk = i * 256 + t;
            int r = chunk >> 4;             // 16 chunks per 64-col row
            int c = (chunk & 15) << 2;
            float4 va = *(const float4*)(centers + (size_t)(m0 + r) * DIM + k0 + c);
            ushort4 pa;
            pa.x = f2b(va.x); pa.y = f2b(va.y); pa.z = f2b(va.z); pa.w = f2b(va.w);
            *(ushort4*)(&sA[r * LDS_STRIDE + c]) = pa;
            float4 vb = *(const float4*)(inputs + (size_t)(n0 + r) * DIM + k0 + c);
            ushort4 pb;
            pb.x = f2b(vb.x); pb.y = f2b(vb.y); pb.z = f2b(vb.z); pb.w = f2b(vb.w);
            *(ushort4*)(&sB[r * LDS_STRIDE + c]) = pb;
        }
        __syncthreads();

        #pragma unroll
        for (int kk = 0; kk < BK; kk += 32) {
            const int col = kk + ((lane >> 4) << 3);     // quad*8
            const int ra  = wm + (lane & 15);
            const int rb  = wn + (lane & 15);
            bf16x8 af[4], bfr[4];
            #pragma unroll
            for (int mi = 0; mi < 4; ++mi)
                af[mi] = *(const bf16x8*)(&sA[(ra + mi * 16) * LDS_STRIDE + col]);
            #pragma unroll
            for (int ni = 0; ni < 4; ++ni)
                bfr[ni] = *(const bf16x8*)(&sB[(rb + ni * 16) * LDS_STRIDE + col]);
            #pragma unroll
            for (int mi = 0; mi < 4; ++mi)
                #pragma unroll
                for (int ni = 0; ni < 4; ++ni)
                    acc[mi][ni] = __builtin_amdgcn_mfma_f32_16x16x32_bf16(
                        af[mi], bfr[ni], acc[mi][ni], 0, 0, 0);
        }
        __syncthreads();
    }

    // epilogue: C/D layout col = lane&15 (n), row = (lane>>4)*4 + reg (m)
    const int ln = lane & 15;
    const int lq = lane >> 4;
    #pragma unroll
    for (int ni = 0; ni < 4; ++ni) {
        const int n = n0 + wn + ni * 16 + ln;
        const float xs = x_sq[n];
        #pragma unroll
        for (int mi = 0; mi < 4; ++mi) {
            const int mbase = m0 + wm + mi * 16 + lq * 4;
            #pragma unroll
            for (int r = 0; r < 4; ++r) {
                const int m = mbase + r;
                out[(size_t)m * N_ROWS + n] = 2.0f * acc[mi][ni][r] - c_sq[m] - xs;
            }
        }
    }
}

extern "C" void kernel_launch(void* const* d_in, const int* in_sizes, int n_in,
                              void* d_out, int out_size, void* d_ws, size_t ws_size,
                              hipStream_t stream) {
    const float* inputs  = (const float*)d_in[0];   // (8192, 1024) fp32
    const float* centers = (const float*)d_in[1];   // (1024, 1024) fp32
    float* out  = (float*)d_out;                    // (1024, 8192) fp32
    float* x_sq = (float*)d_ws;                     // 8192 floats
    float* c_sq = x_sq + N_ROWS;                    // 1024 floats

    norms_kernel<<<N_ROWS + K_CENT, 256, 0, stream>>>(inputs, centers, x_sq, c_sq);
    gemm_kernel<<<dim3(N_ROWS / BN, K_CENT / BM), 256, 0, stream>>>(
        inputs, centers, x_sq, c_sq, out);
}

// Round 2
// 109.414 us; speedup vs baseline: 1.0636x; 1.0636x over previous
//
#include <hip/hip_runtime.h>
#include <hip/hip_bf16.h>

#define N_ROWS 8192   // inputs rows (n)
#define K_CENT 1024   // centers rows (m)
#define DIM    1024   // d

typedef __attribute__((ext_vector_type(8))) __bf16 bf16x8;
typedef __attribute__((ext_vector_type(4))) float  f32x4;

__device__ __forceinline__ unsigned short f2b(float f) {
    union { float f; unsigned u; } x; x.f = f;
    unsigned r = x.u + 0x7FFFu + ((x.u >> 16) & 1u);   // RNE to bf16
    return (unsigned short)(r >> 16);
}

__device__ __forceinline__ void async_copy16(const void* g, void* l) {
    __builtin_amdgcn_global_load_lds(
        (const __attribute__((address_space(1))) unsigned int*)g,
        (__attribute__((address_space(3))) unsigned int*)l,
        16, 0, 0);
}

// ---- kernel 1: fp32 -> bf16 conversion + row norms (norms fp32-exact) ----
// one block per row; rows [0, N_ROWS) = inputs -> Bbf, rest = centers -> Abf
__global__ __launch_bounds__(256) void prep_kernel(
        const float* __restrict__ inputs, const float* __restrict__ centers,
        unsigned short* __restrict__ Bbf, unsigned short* __restrict__ Abf,
        float* __restrict__ x_sq, float* __restrict__ c_sq) {
    const int row = blockIdx.x;
    const bool is_x = row < N_ROWS;
    const float* src = is_x ? (inputs + (size_t)row * DIM)
                            : (centers + (size_t)(row - N_ROWS) * DIM);
    unsigned short* dst = is_x ? (Bbf + (size_t)row * DIM)
                               : (Abf + (size_t)(row - N_ROWS) * DIM);
    const int t = threadIdx.x;
    float4 v = ((const float4*)src)[t];         // 256 thr * 4 = 1024 elems
    ushort4 p;
    p.x = f2b(v.x); p.y = f2b(v.y); p.z = f2b(v.z); p.w = f2b(v.w);
    ((ushort4*)dst)[t] = p;
    float s = v.x*v.x + v.y*v.y + v.z*v.z + v.w*v.w;
    #pragma unroll
    for (int off = 32; off > 0; off >>= 1) s += __shfl_down(s, off, 64);
    __shared__ float wsum[4];
    if ((t & 63) == 0) wsum[t >> 6] = s;
    __syncthreads();
    if (t == 0) {
        float tot = wsum[0] + wsum[1] + wsum[2] + wsum[3];
        if (is_x) x_sq[row] = tot;
        else      c_sq[row - N_ROWS] = tot;
    }
}

// ---- kernel 2: bf16 MFMA GEMM (global_load_lds staging) + epilogue ----
// out[m][n] = 2 * sum_d A[m][d]*B[n][d] - c_sq[m] - x_sq[n]
// 128x128 tile, 4 waves (each 64x64 via 4x4 grid of 16x16x32 MFMAs), BK=64.
// LDS layout: 16B chunks, XOR-swizzled: chunk(r, c8) stored at r*8 + (c8^(r&7)).
#define BM 128
#define BN 128
#define BK 64

__global__ __launch_bounds__(256) void gemm_kernel(
        const unsigned short* __restrict__ Abf,  // K_CENT x DIM bf16
        const unsigned short* __restrict__ Bbf,  // N_ROWS x DIM bf16
        const float* __restrict__ x_sq, const float* __restrict__ c_sq,
        float* __restrict__ out) {               // K_CENT x N_ROWS
    __shared__ unsigned short sA[BM * BK];       // 16 KB
    __shared__ unsigned short sB[BN * BK];       // 16 KB

    const int t    = threadIdx.x;
    const int lane = t & 63;
    const int wave = t >> 6;
    const int wm   = (wave >> 1) * 64;
    const int wn   = (wave & 1) * 64;
    const int m0   = blockIdx.y * BM;
    const int n0   = blockIdx.x * BN;
    const int quad = lane >> 4;
    const int l16  = lane & 15;

    f32x4 acc[4][4] = {};                        // [mi][ni]

    for (int k0 = 0; k0 < DIM; k0 += BK) {
        // stage: 1024 chunks of 16B per matrix; 4 issues x 4 waves x 64 lanes
        #pragma unroll
        for (int i = 0; i < 4; ++i) {
            const int p  = i * 256 + wave * 64 + lane;   // phys chunk (lds = uniform + lane*16)
            const int r  = p >> 3;
            const int c8 = (p & 7) ^ (r & 7);            // logical chunk col
            async_copy16(Abf + (size_t)(m0 + r) * DIM + k0 + c8 * 8, sA + p * 8);
            async_copy16(Bbf + (size_t)(n0 + r) * DIM + k0 + c8 * 8, sB + p * 8);
        }
        __syncthreads();

        #pragma unroll
        for (int kk8 = 0; kk8 < 8; kk8 += 4) {           // two K=32 groups
            bf16x8 af[4], bfr[4];
            #pragma unroll
            for (int mi = 0; mi < 4; ++mi) {
                const int ra = wm + mi * 16 + l16;
                const int pc = ra * 8 + ((kk8 + quad) ^ (ra & 7));
                af[mi] = *(const bf16x8*)(sA + pc * 8);
            }
            #pragma unroll
            for (int ni = 0; ni < 4; ++ni) {
                const int rb = wn + ni * 16 + l16;
                const int pc = rb * 8 + ((kk8 + quad) ^ (rb & 7));
                bfr[ni] = *(const bf16x8*)(sB + pc * 8);
            }
            #pragma unroll
            for (int mi = 0; mi < 4; ++mi)
                #pragma unroll
                for (int ni = 0; ni < 4; ++ni)
                    acc[mi][ni] = __builtin_amdgcn_mfma_f32_16x16x32_bf16(
                        af[mi], bfr[ni], acc[mi][ni], 0, 0, 0);
        }
        __syncthreads();
    }

    // epilogue: C/D layout col(n) = lane&15, row(m) = (lane>>4)*4 + reg
    #pragma unroll
    for (int ni = 0; ni < 4; ++ni) {
        const int n = n0 + wn + ni * 16 + l16;
        const float xs = x_sq[n];
        #pragma unroll
        for (int mi = 0; mi < 4; ++mi) {
            const int mbase = m0 + wm + mi * 16 + quad * 4;
            #pragma unroll
            for (int r = 0; r < 4; ++r) {
                const int m = mbase + r;
                out[(size_t)m * N_ROWS + n] = 2.0f * acc[mi][ni][r] - c_sq[m] - xs;
            }
        }
    }
}

extern "C" void kernel_launch(void* const* d_in, const int* in_sizes, int n_in,
                              void* d_out, int out_size, void* d_ws, size_t ws_size,
                              hipStream_t stream) {
    const float* inputs  = (const float*)d_in[0];   // (8192, 1024) fp32
    const float* centers = (const float*)d_in[1];   // (1024, 1024) fp32
    float* out = (float*)d_out;                     // (1024, 8192) fp32

    // workspace layout (18.9 MB + 36 KB)
    unsigned short* Abf = (unsigned short*)d_ws;            // centers bf16: 1024x1024
    unsigned short* Bbf = Abf + (size_t)K_CENT * DIM;       // inputs  bf16: 8192x1024
    float* x_sq = (float*)(Bbf + (size_t)N_ROWS * DIM);     // 8192
    float* c_sq = x_sq + N_ROWS;                            // 1024

    prep_kernel<<<N_ROWS + K_CENT, 256, 0, stream>>>(inputs, centers, Bbf, Abf, x_sq, c_sq);
    gemm_kernel<<<dim3(N_ROWS / BN, K_CENT / BM), 256, 0, stream>>>(
        Abf, Bbf, x_sq, c_sq, out);
}

// Round 3
// 106.730 us; speedup vs baseline: 1.0904x; 1.0251x over previous
//
#include <hip/hip_runtime.h>
#include <hip/hip_bf16.h>

#define N_ROWS 8192   // inputs rows (n)
#define K_CENT 1024   // centers rows (m)
#define DIM    1024   // d

typedef __attribute__((ext_vector_type(8))) __bf16 bf16x8;
typedef __attribute__((ext_vector_type(4))) float  f32x4;

__device__ __forceinline__ unsigned short f2b(float f) {
    union { float f; unsigned u; } x; x.f = f;
    unsigned r = x.u + 0x7FFFu + ((x.u >> 16) & 1u);   // RNE to bf16
    return (unsigned short)(r >> 16);
}

__device__ __forceinline__ void async_copy16(const void* g, void* l) {
    __builtin_amdgcn_global_load_lds(
        (const __attribute__((address_space(1))) unsigned int*)g,
        (__attribute__((address_space(3))) unsigned int*)l,
        16, 0, 0);
}

// ---- kernel 1: fp32 -> bf16 conversion + row norms. One WAVE per row ----
__global__ __launch_bounds__(256) void prep_kernel(
        const float* __restrict__ inputs, const float* __restrict__ centers,
        unsigned short* __restrict__ Bbf, unsigned short* __restrict__ Abf,
        float* __restrict__ x_sq, float* __restrict__ c_sq) {
    const int row  = blockIdx.x * 4 + (threadIdx.x >> 6);
    const int lane = threadIdx.x & 63;
    const bool is_x = row < N_ROWS;
    const float* src = is_x ? (inputs + (size_t)row * DIM)
                            : (centers + (size_t)(row - N_ROWS) * DIM);
    unsigned short* dst = is_x ? (Bbf + (size_t)row * DIM)
                               : (Abf + (size_t)(row - N_ROWS) * DIM);
    float s = 0.0f;
    #pragma unroll
    for (int j = 0; j < 4; ++j) {
        float4 v = ((const float4*)src)[j * 64 + lane];
        ushort4 p;
        p.x = f2b(v.x); p.y = f2b(v.y); p.z = f2b(v.z); p.w = f2b(v.w);
        ((ushort4*)dst)[j * 64 + lane] = p;
        s += v.x*v.x + v.y*v.y + v.z*v.z + v.w*v.w;
    }
    #pragma unroll
    for (int off = 32; off > 0; off >>= 1) s += __shfl_down(s, off, 64);
    if (lane == 0) {
        if (is_x) x_sq[row] = s;
        else      c_sq[row - N_ROWS] = s;
    }
}

// ---- kernel 2: bf16 MFMA GEMM, double-buffered global_load_lds ----
// out[m][n] = 2 * sum_d A[m][d]*B[n][d] - c_sq[m] - x_sq[n]
// 128x128 tile, 4 waves (each 64x64 via 4x4 of 16x16x32 MFMAs), BK=64.
// LDS: 16B chunks, XOR swizzle: chunk(r,c8) at phys r*8 + (c8^(r&7)).
// Prefetch for iter t+1 issued right after the barrier that publishes iter t,
// so the vmcnt(0) drain at the NEXT barrier is a full compute phase later.
#define BM 128
#define BN 128
#define BK 64
#define NITER (DIM / BK)

__global__ __launch_bounds__(256, 2) void gemm_kernel(
        const unsigned short* __restrict__ Abf,  // K_CENT x DIM bf16
        const unsigned short* __restrict__ Bbf,  // N_ROWS x DIM bf16
        const float* __restrict__ x_sq, const float* __restrict__ c_sq,
        float* __restrict__ out) {               // K_CENT x N_ROWS
    __shared__ unsigned short sA[2][BM * BK];    // 2 x 16 KB
    __shared__ unsigned short sB[2][BN * BK];    // 2 x 16 KB

    const int t    = threadIdx.x;
    const int lane = t & 63;
    const int wave = t >> 6;
    const int wm   = (wave >> 1) * 64;
    const int wn   = (wave & 1) * 64;
    const int m0   = blockIdx.y * BM;
    const int n0   = blockIdx.x * BN;
    const int quad = lane >> 4;
    const int l16  = lane & 15;

    // staging source pointers (advance 64 elems per iter); dest offsets fixed
    const unsigned short* gA[4];
    const unsigned short* gB[4];
    int ldsOff[4];
    #pragma unroll
    for (int i = 0; i < 4; ++i) {
        const int p  = i * 256 + t;
        const int r  = p >> 3;
        const int c8 = (p & 7) ^ (r & 7);
        gA[i] = Abf + (size_t)(m0 + r) * DIM + c8 * 8;
        gB[i] = Bbf + (size_t)(n0 + r) * DIM + c8 * 8;
        ldsOff[i] = p * 8;
    }

    f32x4 acc[4][4] = {};                        // [mi][ni]

    // prologue: stage tile 0 into buf 0
    #pragma unroll
    for (int i = 0; i < 4; ++i) {
        async_copy16(gA[i], &sA[0][ldsOff[i]]);
        async_copy16(gB[i], &sB[0][ldsOff[i]]);
    }

    for (int it = 0; it < NITER; ++it) {
        __syncthreads();   // publishes buf it&1; drains loads issued one compute phase ago

        if (it + 1 < NITER) {
            const int nb = (it + 1) & 1;
            const int koff = (it + 1) * BK;
            #pragma unroll
            for (int i = 0; i < 4; ++i) {
                async_copy16(gA[i] + koff, &sA[nb][ldsOff[i]]);
                async_copy16(gB[i] + koff, &sB[nb][ldsOff[i]]);
            }
        }

        const unsigned short* A = sA[it & 1];
        const unsigned short* B = sB[it & 1];
        #pragma unroll
        for (int kk8 = 0; kk8 < 8; kk8 += 4) {           // two K=32 groups
            bf16x8 af[4], bfr[4];
            #pragma unroll
            for (int mi = 0; mi < 4; ++mi) {
                const int ra = wm + mi * 16 + l16;
                const int pc = ra * 8 + ((kk8 + quad) ^ (ra & 7));
                af[mi] = *(const bf16x8*)(A + pc * 8);
            }
            #pragma unroll
            for (int ni = 0; ni < 4; ++ni) {
                const int rb = wn + ni * 16 + l16;
                const int pc = rb * 8 + ((kk8 + quad) ^ (rb & 7));
                bfr[ni] = *(const bf16x8*)(B + pc * 8);
            }
            #pragma unroll
            for (int mi = 0; mi < 4; ++mi)
                #pragma unroll
                for (int ni = 0; ni < 4; ++ni)
                    acc[mi][ni] = __builtin_amdgcn_mfma_f32_16x16x32_bf16(
                        af[mi], bfr[ni], acc[mi][ni], 0, 0, 0);
        }
    }

    // epilogue: C/D layout col(n) = lane&15, row(m) = (lane>>4)*4 + reg
    #pragma unroll
    for (int ni = 0; ni < 4; ++ni) {
        const int n = n0 + wn + ni * 16 + l16;
        const float xs = x_sq[n];
        #pragma unroll
        for (int mi = 0; mi < 4; ++mi) {
            const int mbase = m0 + wm + mi * 16 + quad * 4;
            #pragma unroll
            for (int r = 0; r < 4; ++r) {
                const int m = mbase + r;
                out[(size_t)m * N_ROWS + n] = 2.0f * acc[mi][ni][r] - c_sq[m] - xs;
            }
        }
    }
}

extern "C" void kernel_launch(void* const* d_in, const int* in_sizes, int n_in,
                              void* d_out, int out_size, void* d_ws, size_t ws_size,
                              hipStream_t stream) {
    const float* inputs  = (const float*)d_in[0];   // (8192, 1024) fp32
    const float* centers = (const float*)d_in[1];   // (1024, 1024) fp32
    float* out = (float*)d_out;                     // (1024, 8192) fp32

    unsigned short* Abf = (unsigned short*)d_ws;            // centers bf16
    unsigned short* Bbf = Abf + (size_t)K_CENT * DIM;       // inputs bf16
    float* x_sq = (float*)(Bbf + (size_t)N_ROWS * DIM);     // 8192
    float* c_sq = x_sq + N_ROWS;                            // 1024

    prep_kernel<<<(N_ROWS + K_CENT) / 4, 256, 0, stream>>>(
        inputs, centers, Bbf, Abf, x_sq, c_sq);
    gemm_kernel<<<dim3(N_ROWS / BN, K_CENT / BM), 256, 0, stream>>>(
        Abf, Bbf, x_sq, c_sq, out);
}

// Round 4
// 96.273 us; speedup vs baseline: 1.2088x; 1.1086x over previous
//
#include <hip/hip_runtime.h>
#include <hip/hip_bf16.h>

#define N_ROWS 8192   // inputs rows (n)
#define K_CENT 1024   // centers rows (m)
#define DIM    1024   // d (elements; == bytes in fp8)

typedef __attribute__((ext_vector_type(4))) float f32x4;
typedef __attribute__((ext_vector_type(8))) int   i32x8;
typedef __attribute__((ext_vector_type(4))) int   i32x4;

__device__ __forceinline__ void async_copy16(const void* g, void* l) {
    __builtin_amdgcn_global_load_lds(
        (const __attribute__((address_space(1))) unsigned int*)g,
        (__attribute__((address_space(3))) unsigned int*)l,
        16, 0, 0);
}

// ---- kernel 1: fp32 -> fp8 e4m3 (scale fixed at 2^0) + fp32-exact row norms ----
// one wave per row; lane handles 16 contiguous elems (64 B read, 16 B write)
__global__ __launch_bounds__(256) void prep_kernel(
        const float* __restrict__ inputs, const float* __restrict__ centers,
        unsigned char* __restrict__ Bq, unsigned char* __restrict__ Aq,
        float* __restrict__ x_sq, float* __restrict__ c_sq) {
    const int row  = blockIdx.x * 4 + (threadIdx.x >> 6);
    const int lane = threadIdx.x & 63;
    const bool is_x = row < N_ROWS;
    const float* src = is_x ? (inputs + (size_t)row * DIM)
                            : (centers + (size_t)(row - N_ROWS) * DIM);
    unsigned char* dst = is_x ? (Bq + (size_t)row * DIM)
                              : (Aq + (size_t)(row - N_ROWS) * DIM);
    const float4* s4 = (const float4*)src + lane * 4;
    float s = 0.0f;
    unsigned w[4];
    #pragma unroll
    for (int j = 0; j < 4; ++j) {
        float4 v = s4[j];
        int pk = __builtin_amdgcn_cvt_pk_fp8_f32(v.x, v.y, 0, false);
        pk     = __builtin_amdgcn_cvt_pk_fp8_f32(v.z, v.w, pk, true);
        w[j] = (unsigned)pk;
        s += v.x*v.x + v.y*v.y + v.z*v.z + v.w*v.w;
    }
    *(uint4*)(dst + lane * 16) = make_uint4(w[0], w[1], w[2], w[3]);
    #pragma unroll
    for (int off = 32; off > 0; off >>= 1) s += __shfl_down(s, off, 64);
    if (lane == 0) {
        if (is_x) x_sq[row] = s;
        else      c_sq[row - N_ROWS] = s;
    }
}

// ---- kernel 2: MX-fp8 MFMA GEMM (16x16x128, scale=2^0), dbuf global_load_lds ----
// out[m][n] = 2 * sum_d A[m][d]*B[n][d] - c_sq[m] - x_sq[n]
// 128x128 tile, 4 waves (each 64x64 via 4x4 of 16x16x128 MFMAs), BK=128 (1 MFMA step/iter).
// LDS: rows of 128 B = 8 x 16-B units; unit h of row r stored at phys h^(r&7).
#define BM 128
#define BN 128
#define BK 128
#define NITER (DIM / BK)

__device__ __forceinline__ i32x8 read_frag(const unsigned char* base, int rowByte,
                                           int off1, int off2) {
    i32x4 lo = *(const i32x4*)(base + rowByte + off1);
    i32x4 hi = *(const i32x4*)(base + rowByte + off2);
    i32x8 f;
    f[0]=lo[0]; f[1]=lo[1]; f[2]=lo[2]; f[3]=lo[3];
    f[4]=hi[0]; f[5]=hi[1]; f[6]=hi[2]; f[7]=hi[3];
    return f;
}

__global__ __launch_bounds__(256, 2) void gemm_kernel(
        const unsigned char* __restrict__ Aq,   // K_CENT x DIM fp8
        const unsigned char* __restrict__ Bq,   // N_ROWS x DIM fp8
        const float* __restrict__ x_sq, const float* __restrict__ c_sq,
        float* __restrict__ out) {              // K_CENT x N_ROWS
    __shared__ unsigned char sA[2][BM * BK];    // 2 x 16 KB
    __shared__ unsigned char sB[2][BN * BK];    // 2 x 16 KB

    const int t    = threadIdx.x;
    const int lane = t & 63;
    const int wave = t >> 6;
    const int wm   = (wave >> 1) * 64;
    const int wn   = (wave & 1) * 64;
    const int m0   = blockIdx.y * BM;
    const int n0   = blockIdx.x * BN;
    const int quad = lane >> 4;
    const int l16  = lane & 15;

    // staging: 1024 16-B units per matrix per iter; 4 per thread per matrix
    const unsigned char* gA[4];
    const unsigned char* gB[4];
    int ldsOff[4];
    #pragma unroll
    for (int i = 0; i < 4; ++i) {
        const int p = i * 256 + t;          // phys unit index
        const int r = p >> 3;               // row 0..127
        const int h = (p & 7) ^ (r & 7);    // logical 16-B unit in row
        gA[i] = Aq + (size_t)(m0 + r) * DIM + h * 16;
        gB[i] = Bq + (size_t)(n0 + r) * DIM + h * 16;
        ldsOff[i] = p * 16;
    }

    // fragment phys offsets: lane wants bytes [quad*32, quad*32+32) of its row
    const int off1 = (((quad << 1)    ) ^ (l16 & 7)) << 4;
    const int off2 = (((quad << 1) | 1) ^ (l16 & 7)) << 4;

    f32x4 acc[4][4] = {};                   // [mi][ni]

    #pragma unroll
    for (int i = 0; i < 4; ++i) {
        async_copy16(gA[i], &sA[0][ldsOff[i]]);
        async_copy16(gB[i], &sB[0][ldsOff[i]]);
    }

    for (int it = 0; it < NITER; ++it) {
        __syncthreads();                    // publishes buf it&1

        if (it + 1 < NITER) {
            const int nb = (it + 1) & 1;
            const int koff = (it + 1) * BK;
            #pragma unroll
            for (int i = 0; i < 4; ++i) {
                async_copy16(gA[i] + koff, &sA[nb][ldsOff[i]]);
                async_copy16(gB[i] + koff, &sB[nb][ldsOff[i]]);
            }
        }

        const unsigned char* A = sA[it & 1];
        const unsigned char* B = sB[it & 1];
        i32x8 af[4], bf[4];
        #pragma unroll
        for (int mi = 0; mi < 4; ++mi)
            af[mi] = read_frag(A, (wm + mi * 16 + l16) << 7, off1, off2);
        #pragma unroll
        for (int ni = 0; ni < 4; ++ni)
            bf[ni] = read_frag(B, (wn + ni * 16 + l16) << 7, off1, off2);
        #pragma unroll
        for (int mi = 0; mi < 4; ++mi)
            #pragma unroll
            for (int ni = 0; ni < 4; ++ni)
                acc[mi][ni] = __builtin_amdgcn_mfma_scale_f32_16x16x128_f8f6f4(
                    af[mi], bf[ni], acc[mi][ni],
                    0, 0,                    // cbsz=fp8(e4m3), blgp=fp8(e4m3)
                    0, 0x7F7F7F7F,           // scale_a opsel, scale_a = 2^0
                    0, 0x7F7F7F7F);          // scale_b opsel, scale_b = 2^0
    }

    // epilogue: C/D layout (shape-determined): col(n) = lane&15, row(m) = quad*4 + reg
    #pragma unroll
    for (int ni = 0; ni < 4; ++ni) {
        const int n = n0 + wn + ni * 16 + l16;
        const float xs = x_sq[n];
        #pragma unroll
        for (int mi = 0; mi < 4; ++mi) {
            const int mbase = m0 + wm + mi * 16 + quad * 4;
            #pragma unroll
            for (int r = 0; r < 4; ++r) {
                const int m = mbase + r;
                out[(size_t)m * N_ROWS + n] = 2.0f * acc[mi][ni][r] - c_sq[m] - xs;
            }
        }
    }
}

extern "C" void kernel_launch(void* const* d_in, const int* in_sizes, int n_in,
                              void* d_out, int out_size, void* d_ws, size_t ws_size,
                              hipStream_t stream) {
    const float* inputs  = (const float*)d_in[0];   // (8192, 1024) fp32
    const float* centers = (const float*)d_in[1];   // (1024, 1024) fp32
    float* out = (float*)d_out;                     // (1024, 8192) fp32

    unsigned char* Aq = (unsigned char*)d_ws;            // centers fp8: 1 MB
    unsigned char* Bq = Aq + (size_t)K_CENT * DIM;       // inputs fp8: 8 MB
    float* x_sq = (float*)(Bq + (size_t)N_ROWS * DIM);   // 8192
    float* c_sq = x_sq + N_ROWS;                         // 1024

    prep_kernel<<<(N_ROWS + K_CENT) / 4, 256, 0, stream>>>(
        inputs, centers, Bq, Aq, x_sq, c_sq);
    gemm_kernel<<<dim3(N_ROWS / BN, K_CENT / BM), 256, 0, stream>>>(
        Aq, Bq, x_sq, c_sq, out);
}